// Round 3
// baseline (316.272 us; speedup 1.0000x reference)
//
#include <hip/hip_runtime.h>
#include <cmath>

// Problem constants (fixed by setup_inputs)
constexpr int NN = 2;       // batch
constexpr int LL = 2048;    // sequence
constexpr int HH = 8;       // heads
constexpr int EE = 32;      // feature dim == value dim
constexpr int CC = 32;      // chunk length
constexpr int NCH = LL / CC;       // 64 chunks per (n,h)
constexpr int NB  = NN * HH * NCH; // 1024 blocks == 4 blocks/CU on 256 CUs
constexpr int BWD = 10;     // softmax bandwidth
constexpr float EPSF = 1e-6f;
// ws record per chunk: S1[32*32], k1[32], S2[32*32], k2[32] (floats)
constexpr int REC  = 2 * (EE * EE + EE);   // 2112 floats
constexpr int REC4 = REC / 4;              // 528
constexpr int OFF_S1 = 0, OFF_K1 = 1024, OFF_S2 = 1056, OFF_K2 = 2080;
constexpr int SK = EE + 4;   // 36: float4-aligned row stride (144 B)
constexpr int NSCAN = NN * HH * REC;       // 33792 independent scan lanes
constexpr unsigned MAGIC = 0x13579BDFu;    // barrier-init flag (!= ws poison)

// key_lengths cancels (normalized over E after a per-row constant multiply).
// Factorization: with Qf=elu1(q), Kf=elu1(k): Q1n.K1n = qi1*ki1*(Qf.Kf),
// Q2n.K2n = qi2*ki2*sum((qf*kf)^2) — one Kf array serves both branches.

__device__ __forceinline__ float elu1(float x) {
    return x > 0.f ? x + 1.f : __expf(x);   // elu(x)+1
}

// Bounded spins: worst case produces a wrong answer, never a hang.
__device__ __forceinline__ void spin_until_eq(unsigned* p, unsigned val) {
    int spins = 0;
    while (__hip_atomic_load(p, __ATOMIC_RELAXED, __HIP_MEMORY_SCOPE_AGENT) != val) {
        __builtin_amdgcn_s_sleep(2);
        if (++spins > 3000000) break;
    }
}
__device__ __forceinline__ void spin_until_ge(unsigned* p, unsigned val) {
    int spins = 0;
    while (__hip_atomic_load(p, __ATOMIC_RELAXED, __HIP_MEMORY_SCOPE_AGENT) < val) {
        __builtin_amdgcn_s_sleep(2);
        if (++spins > 3000000) break;
    }
}

// ---------------- Single kernel, manual grid barriers ----------------------
// Phase 1: stage chunk into LDS ONCE (K,V,Q + 9 prev rows), feature maps,
//          row sums, then per-chunk record sums -> ws.
// grid barrier (manual, device-scope atomics — graph-capturable)
// Phase 2: exclusive prefix over 64 chunks per (n,h), in-place in ws
//          (register scan; blocks 0..131 active).
// grid barrier
// Phase 3: band online-softmax + factorized linear from the STILL-RESIDENT
//          LDS staging; single store.
// LDS = 28.7 KB/block -> >=4 blocks/CU; __launch_bounds__(256,4) caps VGPR
// at 128 so all 1024 blocks (4/CU x 256 CU) are co-resident -> spin is safe.
__global__ __launch_bounds__(256, 4) void mono_kernel(
    const float* __restrict__ Qin, const float* __restrict__ Kin,
    const float* __restrict__ Vin,
    const float* __restrict__ W1, const float* __restrict__ W2,
    const float* __restrict__ W3, float* __restrict__ ws,
    float* __restrict__ out)
{
    __shared__ float Kf [CC][SK];          // elu1(K)
    __shared__ float Qf [CC][SK];          // elu1(Q)
    __shared__ float Qr [CC][SK];          // raw Q (band dot + Phase C via elu1)
    __shared__ float Vs [CC + 9][SK];      // rows l0-9 .. l0+31
    __shared__ float ki1[CC], ki2[CC], qi1[CC], qi2[CC];
    // raw-K (band) and prefix state (linear): disjoint lifetimes
    __shared__ __align__(16) union {
        float kr[(CC + 9) * SK];           // 1476 floats
        float sp[REC];                     // 2112 floats, ws-record layout
    } U;

    const int b  = blockIdx.x;
    const int c  = b & (NCH - 1);
    const int nh = b >> 6;
    const int h  = nh & 7;
    const int n  = nh >> 3;
    const int l0 = c * CC;
    const int t  = threadIdx.x;
    const int lane = t & 31;
    const int grp  = t >> 5;       // 0..7

    // barrier area: past the 8.7MB record region of ws (poisoned each iter)
    unsigned* bar = (unsigned*)(ws + (size_t)NB * REC);
    // bar[0]=ctr0, bar[16]=ctr1, bar[32]=init flag (64B apart)
    if (b == 0 && t == 0) {
        __hip_atomic_store(&bar[0],  0u,    __ATOMIC_RELAXED, __HIP_MEMORY_SCOPE_AGENT);
        __hip_atomic_store(&bar[16], 0u,    __ATOMIC_RELAXED, __HIP_MEMORY_SCOPE_AGENT);
        __hip_atomic_store(&bar[32], MAGIC, __ATOMIC_RELEASE, __HIP_MEMORY_SCOPE_AGENT);
    }

    // ---------------- Phase 1a: staging + feature maps + row sums ----------
    for (int r = grp; r < CC; r += 8) {
        const int l = l0 + r;
        const int base = ((n * LL + l) * HH + h) * EE + lane;
        const float k = Kin[base];
        const float v = Vin[base];
        const float q = Qin[base];
        const float fk = elu1(k), fk2 = fk * fk;
        const float fq = elu1(q), fq2 = fq * fq;
        float sk1 = fk, sk2 = fk2, sq1 = fq, sq2 = fq2;
        #pragma unroll
        for (int m = 1; m < 32; m <<= 1) {
            sk1 += __shfl_xor(sk1, m, 32);
            sk2 += __shfl_xor(sk2, m, 32);
            sq1 += __shfl_xor(sq1, m, 32);
            sq2 += __shfl_xor(sq2, m, 32);
        }
        Kf[r][lane] = fk;
        Qf[r][lane] = fq;
        Qr[r][lane] = q;
        Vs[9 + r][lane] = v;
        U.kr[(9 + r) * SK + lane] = k;
        if (lane == 0) {
            ki1[r] = 1.f / sk1; ki2[r] = 1.f / sk2;
            qi1[r] = 1.f / sq1; qi2[r] = 1.f / sq2;
        }
    }
    // previous 9 rows of raw K,V for the band window
    for (int idx = t; idx < 9 * 32; idx += 256) {
        const int rr = idx >> 5, ln = idx & 31;
        const int l = l0 - 9 + rr;
        float kv = 0.f, vv = 0.f;
        if (l >= 0) {
            const int gbase = ((n * LL + l) * HH + h) * EE + ln;
            kv = Kin[gbase];
            vv = Vin[gbase];
        }
        U.kr[rr * SK + ln] = kv;
        Vs[rr][ln] = vv;
    }
    __syncthreads();

    // ---------------- Phase 1b: per-chunk record sums -> ws -----------------
    {
        const int e  = t >> 3;          // 0..31
        const int d0 = (t & 7) * 4;     // 0..28
        float4 a1 = {0.f, 0.f, 0.f, 0.f};
        float4 a2 = {0.f, 0.f, 0.f, 0.f};
        float ks1 = 0.f, ks2 = 0.f;
        for (int j = 0; j < CC; ++j) {
            const float kf = Kf[j][e];          // multicast, free
            const float p1 = kf * ki1[j];       // == K1n[j][e]
            const float p2 = kf * kf * ki2[j];  // == K2n[j][e]
            const float4 v = *(const float4*)&Vs[9 + j][d0];
            ks1 += p1; ks2 += p2;
            a1.x += p1 * v.x; a1.y += p1 * v.y; a1.z += p1 * v.z; a1.w += p1 * v.w;
            a2.x += p2 * v.x; a2.y += p2 * v.y; a2.z += p2 * v.z; a2.w += p2 * v.w;
        }
        float* wb = ws + (size_t)b * REC;
        *(float4*)&wb[OFF_S1 + e * EE + d0] = a1;
        *(float4*)&wb[OFF_S2 + e * EE + d0] = a2;
        if ((t & 7) == 0) {
            wb[OFF_K1 + e] = ks1;
            wb[OFF_K2 + e] = ks2;
        }
    }

    // ---------------- grid barrier 1 ----------------------------------------
    __syncthreads();
    if (t == 0) {
        __threadfence();                       // flush block's ws writes (L2 wb)
        spin_until_eq(&bar[32], MAGIC);        // wait for counter init
        __hip_atomic_fetch_add(&bar[0], 1u, __ATOMIC_ACQ_REL, __HIP_MEMORY_SCOPE_AGENT);
        spin_until_ge(&bar[0], (unsigned)NB);
        __threadfence();                       // invalidate stale cache lines
    }
    __syncthreads();

    // ---------------- Phase 2: exclusive prefix over chunks per (n,h) ------
    {
        const int gt = b * 256 + t;
        if (gt < NSCAN) {
            const int g = gt / REC;
            const int e = gt - g * REC;
            float* basep = ws + (size_t)g * NCH * REC + e;
            float run = 0.f;
            {
                float v[32];
                #pragma unroll
                for (int cc = 0; cc < 32; ++cc) v[cc] = basep[(size_t)cc * REC];
                #pragma unroll
                for (int cc = 0; cc < 32; ++cc) {
                    const float x = v[cc];
                    basep[(size_t)cc * REC] = run;
                    run += x;
                }
            }
            {
                float v[32];
                #pragma unroll
                for (int cc = 0; cc < 32; ++cc) v[cc] = basep[(size_t)(32 + cc) * REC];
                #pragma unroll
                for (int cc = 0; cc < 32; ++cc) {
                    const float x = v[cc];
                    basep[(size_t)(32 + cc) * REC] = run;
                    run += x;
                }
            }
        }
    }

    // ---------------- grid barrier 2 ----------------------------------------
    __syncthreads();
    if (t == 0) {
        __threadfence();
        __hip_atomic_fetch_add(&bar[16], 1u, __ATOMIC_ACQ_REL, __HIP_MEMORY_SCOPE_AGENT);
        spin_until_ge(&bar[16], (unsigned)NB);
        __threadfence();
    }
    __syncthreads();

    // ---------------- Phase 3: band + linear from resident LDS --------------
    // own exclusive-prefix record -> registers early (hides under band)
    const float4* wbv = (const float4*)(ws + (size_t)b * REC);
    const float4 s0 = wbv[t];
    const float4 s1 = wbv[256 + t];
    float4 s2 = {0.f, 0.f, 0.f, 0.f};
    if (t < REC4 - 512) s2 = wbv[512 + t];          // last 16

    const int r   = t >> 3;        // row 0..31
    const int sub = t & 7;
    const int d0  = sub * 4;
    const int l   = l0 + r;
    const float4 q4 = *(const float4*)&Qr[r][d0];   // raw Q quad from LDS

    // banded ONLINE softmax, 8-lane cluster per row
    float bnd[4];
    {
        const float temp = 0.17677669529663687f;   // 1/sqrt(32)
        float mx = -INFINITY, den = 0.f;
        float sv0 = 0.f, sv1 = 0.f, sv2 = 0.f, sv3 = 0.f;
        #pragma unroll
        for (int jj = 0; jj < BWD; ++jj) {
            const int j = l - (BWD - 1) + jj;   // global key row
            if (j >= 0) {                        // uniform per 8-lane row group
                const float4 k4 = *(const float4*)&U.kr[(r + jj) * SK + d0];
                float p = q4.x*k4.x + q4.y*k4.y + q4.z*k4.z + q4.w*k4.w;
                p += __shfl_xor(p, 1, 8); p += __shfl_xor(p, 2, 8); p += __shfl_xor(p, 4, 8);
                const float s  = p * temp;
                const float mn = fmaxf(mx, s);
                const float c1 = __expf(mx - mn);   // 0 on first iter
                const float c2 = __expf(s - mn);
                const float4 v4 = *(const float4*)&Vs[r + jj][d0];
                den = den * c1 + c2;
                sv0 = sv0 * c1 + c2 * v4.x;
                sv1 = sv1 * c1 + c2 * v4.y;
                sv2 = sv2 * c1 + c2 * v4.z;
                sv3 = sv3 * c1 + c2 * v4.w;
                mx = mn;
            }
        }
        const float inv = 1.f / den;
        const float4 w1 = *(const float4*)&W1[h * EE + d0];
        bnd[0] = w1.x * sv0 * inv; bnd[1] = w1.y * sv1 * inv;
        bnd[2] = w1.z * sv2 * inv; bnd[3] = w1.w * sv3 * inv;
    }
    __syncthreads();   // all reads of U.kr done

    // publish own prefix record into U.sp (same layout as ws record)
    ((float4*)U.sp)[t]       = s0;
    ((float4*)U.sp)[256 + t] = s1;
    if (t < REC4 - 512) ((float4*)U.sp)[512 + t] = s2;
    __syncthreads();

    const float* S1p = U.sp + OFF_S1;
    const float* S2p = U.sp + OFF_S2;
    const float* k1p = U.sp + OFF_K1;
    const float* k2p = U.sp + OFF_K2;

    const float qi1v = qi1[r];     // multicast
    const float qi2v = qi2[r];
    float4 qf4;                    // elu1(q) recomputed (no extra LDS read)
    qf4.x = elu1(q4.x); qf4.y = elu1(q4.y);
    qf4.z = elu1(q4.z); qf4.w = elu1(q4.w);

    float a1[4] = {0.f, 0.f, 0.f, 0.f};   // unscaled (x qi at end)
    float a2[4] = {0.f, 0.f, 0.f, 0.f};
    float dp1 = 0.f, dp2 = 0.f;

    // prefix contribution: a1 += Qf[e]*S1p[e][:], a2 += Qf[e]^2*S2p[e][:]
    #pragma unroll 4
    for (int e = 0; e < EE; ++e) {
        const float tq  = Qf[r][e];            // multicast
        const float tq2 = tq * tq;
        dp1 += tq  * k1p[e];
        dp2 += tq2 * k2p[e];
        const float4 sa = *(const float4*)&S1p[e * EE + d0];
        const float4 ta = *(const float4*)&S2p[e * EE + d0];
        a1[0] += tq  * sa.x; a1[1] += tq  * sa.y; a1[2] += tq  * sa.z; a1[3] += tq  * sa.w;
        a2[0] += tq2 * ta.x; a2[1] += tq2 * ta.y; a2[2] += tq2 * ta.z; a2[3] += tq2 * ta.w;
    }

    // intra-chunk causal: one Kf read serves both branches
    for (int j = 0; j <= r; ++j) {
        const float4 kf = *(const float4*)&Kf[j][d0];
        const float t0 = qf4.x * kf.x, t1 = qf4.y * kf.y;
        const float t2 = qf4.z * kf.z, t3 = qf4.w * kf.w;
        float u1 = (t0 + t1) + (t2 + t3);
        float u2 = ((t0 * t0 + t1 * t1) + (t2 * t2 + t3 * t3));
        u1 += __shfl_xor(u1, 1, 8); u1 += __shfl_xor(u1, 2, 8); u1 += __shfl_xor(u1, 4, 8);
        u2 += __shfl_xor(u2, 1, 8); u2 += __shfl_xor(u2, 2, 8); u2 += __shfl_xor(u2, 4, 8);
        const float p1 = u1 * ki1[j];          // multicast
        const float p2 = u2 * ki2[j];
        dp1 += p1;
        dp2 += p2;
        const float4 va = *(const float4*)&Vs[9 + j][d0];
        a1[0] += p1 * va.x; a1[1] += p1 * va.y; a1[2] += p1 * va.z; a1[3] += p1 * va.w;
        a2[0] += p2 * va.x; a2[1] += p2 * va.y; a2[2] += p2 * va.z; a2[3] += p2 * va.w;
    }

    const float z1 = qi1v / (qi1v * dp1 + EPSF);
    const float z2 = qi2v / (qi2v * dp2 + EPSF);
    const float4 w2 = *(const float4*)&W2[h * EE + d0];
    const float4 w3 = *(const float4*)&W3[h * EE + d0];
    float4 o;
    o.x = bnd[0] + w2.x * a1[0] * z1 + w3.x * a2[0] * z2;
    o.y = bnd[1] + w2.y * a1[1] * z1 + w3.y * a2[1] * z2;
    o.z = bnd[2] + w2.z * a1[2] * z1 + w3.z * a2[2] * z2;
    o.w = bnd[3] + w2.w * a1[3] * z1 + w3.w * a2[3] * z2;
    *(float4*)&out[((n * LL + l) * HH + h) * EE + d0] = o;
}

extern "C" void kernel_launch(void* const* d_in, const int* in_sizes, int n_in,
                              void* d_out, int out_size, void* d_ws, size_t ws_size,
                              hipStream_t stream)
{
    (void)in_sizes; (void)n_in; (void)out_size; (void)ws_size;
    const float* Q  = (const float*)d_in[0];
    const float* K  = (const float*)d_in[1];
    const float* V  = (const float*)d_in[2];
    // d_in[3] = key_lengths: cancels mathematically (normalization over E)
    const float* W1 = (const float*)d_in[4];
    const float* W2 = (const float*)d_in[5];
    const float* W3 = (const float*)d_in[6];
    float* out = (float*)d_out;
    float* ws  = (float*)d_ws;   // records (8.7MB) + barrier words

    mono_kernel<<<NB, 256, 0, stream>>>(Q, K, V, W1, W2, W3, ws, out);
}

// Round 4
// 101.968 us; speedup vs baseline: 3.1017x; 3.1017x over previous
//
#include <hip/hip_runtime.h>
#include <cmath>

// Problem constants (fixed by setup_inputs)
constexpr int NN = 2;       // batch
constexpr int LL = 2048;    // sequence
constexpr int HH = 8;       // heads
constexpr int EE = 32;      // feature dim == value dim
constexpr int CC = 32;      // chunk length
constexpr int NCH = LL / CC;       // 64 chunks per (n,h)
constexpr int NB  = NN * HH * NCH; // 1024 blocks
constexpr int BWD = 10;     // softmax bandwidth
constexpr float EPSF = 1e-6f;
// ws record per chunk: S1[32*32], k1[32], S2[32*32], k2[32] (floats)
constexpr int REC  = 2 * (EE * EE + EE);   // 2112 floats
constexpr int REC4 = REC / 4;              // 528
constexpr int OFF_S1 = 0, OFF_K1 = 1024, OFF_S2 = 1056, OFF_K2 = 2080;
constexpr int SK = EE + 4;   // 36: float4-aligned f32 row stride (144 B)
constexpr int SB = 40;       // bf16 row stride (80 B, 16B-aligned rows)

using f32x16 = __attribute__((ext_vector_type(16))) float;
using s16x8  = __attribute__((ext_vector_type(8)))  short;

__device__ __forceinline__ float elu1(float x) {
    return x > 0.f ? x + 1.f : __expf(x);   // elu(x)+1
}
// f32 -> bf16 bits, round-to-nearest-even (inputs finite)
__device__ __forceinline__ unsigned short bfr(float x) {
    union { float f; unsigned u; } v; v.f = x;
    return (unsigned short)((v.u + 0x7FFFu + ((v.u >> 16) & 1u)) >> 16);
}
__device__ __forceinline__ float bf2f(unsigned short b) {
    union { unsigned u; float f; } v; v.u = ((unsigned)b) << 16;
    return v.f;
}

// ---------------- Kernel 1: per-chunk state sums -> ws (verbatim R0) --------
__global__ __launch_bounds__(256) void chunksum_kernel(
    const float* __restrict__ Kin, const float* __restrict__ Vin,
    float* __restrict__ ws)
{
    __shared__ float K1n[CC][SK];
    __shared__ float K2n[CC][SK];
    __shared__ float Vs [CC][SK];

    const int b  = blockIdx.x;
    const int c  = b & (NCH - 1);
    const int nh = b >> 6;
    const int t  = threadIdx.x;
    const int lane = t & 31;
    const int grp  = t >> 5;    // 0..7

    for (int r = grp; r < CC; r += 8) {
        const int l = c * CC + r;
        const int base = ((nh >> 3) * LL + l) * HH * EE + (nh & 7) * EE + lane;
        const float k = Kin[base];
        const float v = Vin[base];
        const float f1 = elu1(k);
        const float f2 = f1 * f1;
        float s1 = f1, s2 = f2;
        #pragma unroll
        for (int m = 1; m < 32; m <<= 1) {
            s1 += __shfl_xor(s1, m, 32);
            s2 += __shfl_xor(s2, m, 32);
        }
        K1n[r][lane] = f1 / s1;
        K2n[r][lane] = f2 / s2;
        Vs [r][lane] = v;
    }
    __syncthreads();

    const int e  = t >> 3;          // 0..31
    const int d0 = (t & 7) * 4;     // 0..28
    float4 a1 = {0.f, 0.f, 0.f, 0.f};
    float4 a2 = {0.f, 0.f, 0.f, 0.f};
    float ks1 = 0.f, ks2 = 0.f;
    for (int j = 0; j < CC; ++j) {
        const float k1 = K1n[j][e];     // multicast, free
        const float k2 = K2n[j][e];
        const float4 v = *(const float4*)&Vs[j][d0];
        ks1 += k1; ks2 += k2;
        a1.x += k1 * v.x; a1.y += k1 * v.y; a1.z += k1 * v.z; a1.w += k1 * v.w;
        a2.x += k2 * v.x; a2.y += k2 * v.y; a2.z += k2 * v.z; a2.w += k2 * v.w;
    }
    float* wb = ws + (size_t)b * REC;
    *(float4*)&wb[OFF_S1 + e * EE + d0] = a1;
    *(float4*)&wb[OFF_S2 + e * EE + d0] = a2;
    if ((t & 7) == 0) {
        wb[OFF_K1 + e] = ks1;
        wb[OFF_K2 + e] = ks2;
    }
}

// ---------------- Kernel 2: exclusive prefix over chunks (verbatim R0) ------
__global__ __launch_bounds__(192) void prefix_kernel(float* __restrict__ ws)
{
    const int g = blockIdx.x / 11;
    const int e = (blockIdx.x % 11) * 192 + threadIdx.x;   // 0..2111
    float* base = ws + (size_t)g * NCH * REC + e;
    float run = 0.f;
    {
        float v[32];
        #pragma unroll
        for (int c = 0; c < 32; ++c) v[c] = base[(size_t)c * REC];
        #pragma unroll
        for (int c = 0; c < 32; ++c) {
            const float x = v[c];
            base[(size_t)c * REC] = run;
            run += x;
        }
    }
    {
        float v[32];
        #pragma unroll
        for (int c = 0; c < 32; ++c) v[c] = base[(size_t)(32 + c) * REC];
        #pragma unroll
        for (int c = 0; c < 32; ++c) {
            const float x = v[c];
            base[(size_t)(32 + c) * REC] = run;
            run += x;
        }
    }
}

// ---------------- Kernel 3: band (scalar, verbatim) + linear via MFMA -------
// Phase C rewritten as bf16 MFMA (f32 accum). Per block, per branch (10 mfma):
//   P  = Qf x Kn^T          (masked j<=r; Kn has ki folded in)
//   A  = P x V + Qf x S     (triangle + prefix)
//   dp = P x Ones + Qf x krep  (ones-trick: rowsum replicated over cols,
//                               SAME C/D layout as A -> per-element z scale)
// C/D layout (guide-verified): col=lane&31, row=(reg&3)+8*(reg>>2)+4*(lane>>5).
// A frag: row=lane&31, k=8*(lane>>5)+idx.  B frag: col=lane&31, same k-run.
// Wave 0 does branch 1, wave 2 branch 2; waves 1,3 idle through Phase C.
__global__ __launch_bounds__(256) void fused_kernel(
    const float* __restrict__ Qin, const float* __restrict__ Kin,
    const float* __restrict__ Vin,
    const float* __restrict__ W1, const float* __restrict__ W2,
    const float* __restrict__ W3, const float* __restrict__ ws,
    float* __restrict__ out)
{
    __shared__ float Vs [CC + 9][SK];      // rows l0-9 .. l0+31 (f32, band+V-frags)
    __shared__ float qi1[CC], qi2[CC];
    __shared__ __align__(16) unsigned short Qfb [CC][SB];  // bf16 elu1(Q)
    __shared__ __align__(16) unsigned short K1nb[CC][SB];  // bf16 fk/sk1
    __shared__ __align__(16) unsigned short K2nb[CC][SB];  // bf16 fk^2/sk2
    __shared__ __align__(16) unsigned short Pb1 [CC][SB];  // P relayout buffers
    __shared__ __align__(16) unsigned short Pb2 [CC][SB];
    __shared__ float Ob1[CC][SK];          // branch outputs (w*z applied)
    __shared__ float Ob2[CC][SK];
    // raw-K (band) and prefix state (linear): disjoint lifetimes
    __shared__ __align__(16) union {
        float kr[(CC + 9) * SK];           // 1476 floats
        float sp[REC];                     // 2112 floats, ws-record layout
    } U;

    const int b  = blockIdx.x;
    const int c  = b & (NCH - 1);
    const int nh = b >> 6;
    const int h  = nh & 7;
    const int n  = nh >> 3;
    const int l0 = c * CC;
    const int t  = threadIdx.x;
    const int lane = t & 31;
    const int grp  = t >> 5;       // 0..7

    // own exclusive-prefix record -> registers early (hides under A/B)
    const float4* wbv = (const float4*)(ws + (size_t)b * REC);
    const float4 s0 = wbv[t];
    const float4 s1 = wbv[256 + t];
    float4 s2 = {0.f, 0.f, 0.f, 0.f};
    if (t < REC4 - 512) s2 = wbv[512 + t];          // last 16

    // ---------------- Phase A: staging + feature maps + row sums -------------
    for (int r = grp; r < CC; r += 8) {
        const int l = l0 + r;
        const int base = ((n * LL + l) * HH + h) * EE + lane;
        const float k = Kin[base];
        const float v = Vin[base];
        const float q = Qin[base];
        const float fk = elu1(k), fk2 = fk * fk;
        const float fq = elu1(q), fq2 = fq * fq;
        float sk1 = fk, sk2 = fk2, sq1 = fq, sq2 = fq2;
        #pragma unroll
        for (int m = 1; m < 32; m <<= 1) {
            sk1 += __shfl_xor(sk1, m, 32);
            sk2 += __shfl_xor(sk2, m, 32);
            sq1 += __shfl_xor(sq1, m, 32);
            sq2 += __shfl_xor(sq2, m, 32);
        }
        const float is1 = __builtin_amdgcn_rcpf(sk1);   // >0 always
        const float is2 = __builtin_amdgcn_rcpf(sk2);
        Qfb [r][lane] = bfr(fq);
        K1nb[r][lane] = bfr(fk  * is1);
        K2nb[r][lane] = bfr(fk2 * is2);
        Vs[9 + r][lane] = v;
        U.kr[(9 + r) * SK + lane] = k;
        if (lane == 0) {
            qi1[r] = 1.f / sq1; qi2[r] = 1.f / sq2;
        }
    }
    // previous 9 rows of raw K,V for the band window
    for (int idx = t; idx < 9 * 32; idx += 256) {
        const int rr = idx >> 5, ln = idx & 31;
        const int l = l0 - 9 + rr;
        float kv = 0.f, vv = 0.f;
        if (l >= 0) {
            const int gbase = ((n * LL + l) * HH + h) * EE + ln;
            kv = Kin[gbase];
            vv = Vin[gbase];
        }
        U.kr[rr * SK + ln] = kv;
        Vs[rr][ln] = vv;
    }

    // cluster identity for band and the final store
    const int r   = t >> 3;        // row 0..31
    const int sub = t & 7;
    const int d0  = sub * 4;
    const int l   = l0 + r;

    // raw Q quad in registers (band dot)
    const float4 q4 = *(const float4*)&Qin[((n * LL + l) * HH + h) * EE + d0];
    __syncthreads();

    // ---------------- Phase B: banded ONLINE softmax, cluster f4 (verbatim) --
    float bnd[4];
    {
        const float temp = 0.17677669529663687f;   // 1/sqrt(32)
        float mx = -INFINITY, den = 0.f;
        float sv0 = 0.f, sv1 = 0.f, sv2 = 0.f, sv3 = 0.f;
        #pragma unroll
        for (int jj = 0; jj < BWD; ++jj) {
            const int j = l - (BWD - 1) + jj;   // global key row
            if (j >= 0) {                        // uniform per 8-lane row group
                const float4 k4 = *(const float4*)&U.kr[(r + jj) * SK + d0];
                float p = q4.x*k4.x + q4.y*k4.y + q4.z*k4.z + q4.w*k4.w;
                p += __shfl_xor(p, 1, 8); p += __shfl_xor(p, 2, 8); p += __shfl_xor(p, 4, 8);
                const float s  = p * temp;
                const float mn = fmaxf(mx, s);
                const float c1 = __expf(mx - mn);   // 0 on first iter
                const float c2 = __expf(s - mn);
                const float4 v4 = *(const float4*)&Vs[r + jj][d0];
                den = den * c1 + c2;
                sv0 = sv0 * c1 + c2 * v4.x;
                sv1 = sv1 * c1 + c2 * v4.y;
                sv2 = sv2 * c1 + c2 * v4.z;
                sv3 = sv3 * c1 + c2 * v4.w;
                mx = mn;
            }
        }
        const float inv = 1.f / den;
        const float4 w1 = *(const float4*)&W1[h * EE + d0];
        bnd[0] = w1.x * sv0 * inv; bnd[1] = w1.y * sv1 * inv;
        bnd[2] = w1.z * sv2 * inv; bnd[3] = w1.w * sv3 * inv;
    }
    __syncthreads();   // all reads of U.kr done

    // publish own prefix record into U.sp (same layout as ws record)
    ((float4*)U.sp)[t]       = s0;
    ((float4*)U.sp)[256 + t] = s1;
    if (t < REC4 - 512) ((float4*)U.sp)[512 + t] = s2;
    __syncthreads();

    // ---------------- Phase C: per-branch MFMA chain (waves 0 and 2) --------
    const int wid = t >> 6;
    const int l64 = t & 63;
    const int l31 = l64 & 31;       // = A-row / B-col / C-col
    const int hi5 = l64 >> 5;       // k-half selector within frags

    if ((wid & 1) == 0) {
        const bool b2 = (wid == 2);
        const unsigned short* Kn = b2 ? &K2nb[0][0] : &K1nb[0][0];
        const float* Sp  = U.sp + (b2 ? OFF_S2 : OFF_S1);
        const float* kp  = U.sp + (b2 ? OFF_K2 : OFF_K1);
        const float* qiv = b2 ? qi2 : qi1;
        const float* Wv  = b2 ? W3  : W2;
        unsigned short* Pb = b2 ? &Pb2[0][0] : &Pb1[0][0];
        float* Ob = b2 ? &Ob2[0][0] : &Ob1[0][0];

        // A-frags: Qf rows (branch2: elementwise square, re-rounded)
        s16x8 qa0 = *(const s16x8*)&Qfb[l31][8 * hi5];
        s16x8 qa1 = *(const s16x8*)&Qfb[l31][16 + 8 * hi5];
        if (b2) {
            #pragma unroll
            for (int i = 0; i < 8; ++i) {
                const float f0 = bf2f((unsigned short)qa0[i]);
                const float f1 = bf2f((unsigned short)qa1[i]);
                qa0[i] = (short)bfr(f0 * f0);
                qa1[i] = (short)bfr(f1 * f1);
            }
        }
        // B-frags: Kn^T  (Kn stored row-major [j][e] -> B[e][j] frag = row read)
        const s16x8 kb0 = *(const s16x8*)&Kn[l31 * SB + 8 * hi5];
        const s16x8 kb1 = *(const s16x8*)&Kn[l31 * SB + 16 + 8 * hi5];

        // P = Qf x Kn^T   (K=32 via two K=16 mfma)
        f32x16 P = {};
        P = __builtin_amdgcn_mfma_f32_32x32x16_bf16(qa0, kb0, P, 0, 0, 0);
        P = __builtin_amdgcn_mfma_f32_32x32x16_bf16(qa1, kb1, P, 0, 0, 0);

        // causal mask (keep j<=r), relayout C/D -> row-major bf16 in LDS
        #pragma unroll
        for (int k = 0; k < 16; ++k) {
            const int row = (k & 3) + 8 * (k >> 2) + 4 * hi5;
            const float pv = (l31 <= row) ? P[k] : 0.f;
            Pb[row * SB + l31] = bfr(pv);
        }
        // A-frags of P (same wave wrote all of Pb; compiler orders via lgkmcnt)
        const s16x8 pa0 = *(const s16x8*)&Pb[l31 * SB + 8 * hi5];
        const s16x8 pa1 = *(const s16x8*)&Pb[l31 * SB + 16 + 8 * hi5];

        // B-frags of V (scalar gather from f32 Vs)
        s16x8 vb0, vb1;
        #pragma unroll
        for (int i = 0; i < 8; ++i) {
            vb0[i] = (short)bfr(Vs[9 + 8 * hi5 + i][l31]);
            vb1[i] = (short)bfr(Vs[9 + 16 + 8 * hi5 + i][l31]);
        }
        // B-frags of S (prefix state, row-major [e][d] in U.sp)
        s16x8 sb0, sb1;
        #pragma unroll
        for (int i = 0; i < 8; ++i) {
            sb0[i] = (short)bfr(Sp[(8 * hi5 + i) * EE + l31]);
            sb1[i] = (short)bfr(Sp[(16 + 8 * hi5 + i) * EE + l31]);
        }
        f32x16 A = {};
        A = __builtin_amdgcn_mfma_f32_32x32x16_bf16(pa0, vb0, A, 0, 0, 0);  // triangle
        A = __builtin_amdgcn_mfma_f32_32x32x16_bf16(pa1, vb1, A, 0, 0, 0);
        A = __builtin_amdgcn_mfma_f32_32x32x16_bf16(qa0, sb0, A, 0, 0, 0);  // prefix
        A = __builtin_amdgcn_mfma_f32_32x32x16_bf16(qa1, sb1, A, 0, 0, 0);

        // dp = rowsum(P) + Qf.kp  (replicated over cols -> same layout as A)
        s16x8 ones;
        #pragma unroll
        for (int i = 0; i < 8; ++i) ones[i] = (short)0x3F80;  // bf16 1.0
        s16x8 rb0, rb1;
        #pragma unroll
        for (int i = 0; i < 8; ++i) {
            rb0[i] = (short)bfr(kp[8 * hi5 + i]);
            rb1[i] = (short)bfr(kp[16 + 8 * hi5 + i]);
        }
        f32x16 Dp = {};
        Dp = __builtin_amdgcn_mfma_f32_32x32x16_bf16(pa0, ones, Dp, 0, 0, 0);
        Dp = __builtin_amdgcn_mfma_f32_32x32x16_bf16(pa1, ones, Dp, 0, 0, 0);
        Dp = __builtin_amdgcn_mfma_f32_32x32x16_bf16(qa0, rb0, Dp, 0, 0, 0);
        Dp = __builtin_amdgcn_mfma_f32_32x32x16_bf16(qa1, rb1, Dp, 0, 0, 0);

        // epilogue: z scale + output weight -> Ob
        const float wv = Wv[h * EE + l31];
        #pragma unroll
        for (int k = 0; k < 16; ++k) {
            const int row = (k & 3) + 8 * (k >> 2) + 4 * hi5;
            const float qi = qiv[row];
            const float z  = qi / (qi * Dp[k] + EPSF);
            Ob[row * SK + l31] = wv * A[k] * z;
        }
    }
    __syncthreads();

    // ---------------- final combine + single store (cluster mapping) --------
    const float4 o1 = *(const float4*)&Ob1[r][d0];
    const float4 o2 = *(const float4*)&Ob2[r][d0];
    float4 o;
    o.x = bnd[0] + o1.x + o2.x;
    o.y = bnd[1] + o1.y + o2.y;
    o.z = bnd[2] + o1.z + o2.z;
    o.w = bnd[3] + o1.w + o2.w;
    *(float4*)&out[((n * LL + l) * HH + h) * EE + d0] = o;
}

extern "C" void kernel_launch(void* const* d_in, const int* in_sizes, int n_in,
                              void* d_out, int out_size, void* d_ws, size_t ws_size,
                              hipStream_t stream)
{
    (void)in_sizes; (void)n_in; (void)out_size; (void)ws_size;
    const float* Q  = (const float*)d_in[0];
    const float* K  = (const float*)d_in[1];
    const float* V  = (const float*)d_in[2];
    // d_in[3] = key_lengths: cancels mathematically (normalization over E)
    const float* W1 = (const float*)d_in[4];
    const float* W2 = (const float*)d_in[5];
    const float* W3 = (const float*)d_in[6];
    float* out = (float*)d_out;
    float* ws  = (float*)d_ws;   // uses NB*REC*4 = ~8.7 MB of scratch

    chunksum_kernel<<<NB,           256, 0, stream>>>(K, V, ws);
    prefix_kernel  <<<NN * HH * 11, 192, 0, stream>>>(ws);
    fused_kernel   <<<NB,           256, 0, stream>>>(Q, K, V, W1, W2, W3, ws, out);
}

// Round 7
// 101.580 us; speedup vs baseline: 3.1135x; 1.0038x over previous
//
#include <hip/hip_runtime.h>
#include <cmath>

// Problem constants (fixed by setup_inputs)
constexpr int NN = 2;       // batch
constexpr int LL = 2048;    // sequence
constexpr int HH = 8;       // heads
constexpr int EE = 32;      // feature dim == value dim
constexpr int CC = 32;      // chunk length
constexpr int NCH = LL / CC;       // 64 chunks per (n,h)
constexpr int NB  = NN * HH * NCH; // 1024 blocks
constexpr int BWD = 10;     // softmax bandwidth
// bf16 record per chunk (shorts): St1[d][e] 32x32, k1[32], St2, k2
// S stored TRANSPOSED (d-major) so fused's B-frags of S are vector reads.
constexpr int REC  = 2 * (EE * EE + EE);   // 2112 shorts = 4224 B (264 x 16B)
constexpr int R16  = REC * 2 / 16;         // 264 16-byte chunks
constexpr int OFF_S1 = 0, OFF_K1 = 1024, OFF_S2 = 1056, OFF_K2 = 2080; // short idx
constexpr int SK = EE + 4;   // 36: float4-aligned f32 row stride (144 B)
constexpr int SB = 40;       // bf16 LDS row stride (80 B, 16B-aligned rows)

using f32x16 = __attribute__((ext_vector_type(16))) float;
using s16x8  = __attribute__((ext_vector_type(8)))  short;

__device__ __forceinline__ float elu1(float x) {
    return x > 0.f ? x + 1.f : __expf(x);   // elu(x)+1
}
// f32 -> bf16 bits, round-to-nearest-even (inputs finite)
__device__ __forceinline__ unsigned short bfr(float x) {
    union { float f; unsigned u; } v; v.f = x;
    return (unsigned short)((v.u + 0x7FFFu + ((v.u >> 16) & 1u)) >> 16);
}
__device__ __forceinline__ float bf2f(unsigned short b) {
    union { unsigned u; float f; } v; v.u = ((unsigned)b) << 16;
    return v.f;
}

// ---------------- Kernel 1: per-chunk state sums -> bf16 ws ------------------
// staging+normalize as before; accumulate thread=(d, e-quad) so the
// TRANSPOSED St[d][e] store is coalesced (ushort4 = 8B per thread).
__global__ __launch_bounds__(256) void chunksum_kernel(
    const float* __restrict__ Kin, const float* __restrict__ Vin,
    unsigned short* __restrict__ ws)
{
    __shared__ float K1n[CC][SK];
    __shared__ float K2n[CC][SK];
    __shared__ float Vs [CC][SK];

    const int b  = blockIdx.x;
    const int c  = b & (NCH - 1);
    const int nh = b >> 6;
    const int t  = threadIdx.x;
    const int lane = t & 31;
    const int grp  = t >> 5;    // 0..7

    for (int r = grp; r < CC; r += 8) {
        const int l = c * CC + r;
        const int base = ((nh >> 3) * LL + l) * HH * EE + (nh & 7) * EE + lane;
        const float k = Kin[base];
        const float v = Vin[base];
        const float f1 = elu1(k);
        const float f2 = f1 * f1;
        float s1 = f1, s2 = f2;
        #pragma unroll
        for (int m = 1; m < 32; m <<= 1) {
            s1 += __shfl_xor(s1, m, 32);
            s2 += __shfl_xor(s2, m, 32);
        }
        K1n[r][lane] = f1 * __builtin_amdgcn_rcpf(s1);   // s1,s2 > 0
        K2n[r][lane] = f2 * __builtin_amdgcn_rcpf(s2);
        Vs [r][lane] = v;
    }
    __syncthreads();

    const int d  = t >> 3;          // 0..31 (value dim)
    const int e0 = (t & 7) * 4;     // 0..28 (feature dim quad)
    float a1x=0.f,a1y=0.f,a1z=0.f,a1w=0.f;
    float a2x=0.f,a2y=0.f,a2z=0.f,a2w=0.f;
    float k1x=0.f,k1y=0.f,k1z=0.f,k1w=0.f;
    float k2x=0.f,k2y=0.f,k2z=0.f,k2w=0.f;
    for (int j = 0; j < CC; ++j) {
        const float vv = Vs[j][d];                      // broadcast, free
        const float4 k1 = *(const float4*)&K1n[j][e0];
        const float4 k2 = *(const float4*)&K2n[j][e0];
        k1x += k1.x; k1y += k1.y; k1z += k1.z; k1w += k1.w;
        k2x += k2.x; k2y += k2.y; k2z += k2.z; k2w += k2.w;
        a1x += vv * k1.x; a1y += vv * k1.y; a1z += vv * k1.z; a1w += vv * k1.w;
        a2x += vv * k2.x; a2y += vv * k2.y; a2z += vv * k2.z; a2w += vv * k2.w;
    }
    unsigned short* wb = ws + (size_t)b * REC;
    ushort4 o1 = { bfr(a1x), bfr(a1y), bfr(a1z), bfr(a1w) };
    ushort4 o2 = { bfr(a2x), bfr(a2y), bfr(a2z), bfr(a2w) };
    *(ushort4*)&wb[OFF_S1 + d * EE + e0] = o1;
    *(ushort4*)&wb[OFF_S2 + d * EE + e0] = o2;
    if (d == 0) {
        ushort4 s1v = { bfr(k1x), bfr(k1y), bfr(k1z), bfr(k1w) };
        ushort4 s2v = { bfr(k2x), bfr(k2y), bfr(k2z), bfr(k2w) };
        *(ushort4*)&wb[OFF_K1 + e0] = s1v;
        *(ushort4*)&wb[OFF_K2 + e0] = s2v;
    }
}

// ---------------- Kernel 2: exclusive prefix over chunks (bf16, f32 carry) --
__global__ __launch_bounds__(192) void prefix_kernel(unsigned short* __restrict__ ws)
{
    const int g = blockIdx.x / 11;
    const int e = (blockIdx.x % 11) * 192 + threadIdx.x;   // 0..2111
    unsigned short* base = ws + (size_t)g * NCH * REC + e;
    float run = 0.f;
    {
        unsigned short v[32];
        #pragma unroll
        for (int c = 0; c < 32; ++c) v[c] = base[(size_t)c * REC];
        #pragma unroll
        for (int c = 0; c < 32; ++c) {
            base[(size_t)c * REC] = bfr(run);
            run += bf2f(v[c]);
        }
    }
    {
        unsigned short v[32];
        #pragma unroll
        for (int c = 0; c < 32; ++c) v[c] = base[(size_t)(32 + c) * REC];
        #pragma unroll
        for (int c = 0; c < 32; ++c) {
            base[(size_t)(32 + c) * REC] = bfr(run);
            run += bf2f(v[c]);
        }
    }
}

// ---------------- Kernel 3: band (scalar) + linear via MFMA ------------------
// Phase A: pure stage (NO shuffles, no ki/qi). Phase C per branch-wave:
//   Dk = ones x Kf^T          -> every lane holds sk[col]; ki = rcp (f32!)
//   P  = Qf x Kf^T            -> normalize by ki per COLUMN at relayout
//   A  = P x V + Qf x S       (S from bf16 transposed record: vector reads)
//   Dp = P x Ones + Qf x kp   (same C/D layout as A)
//   z  = rcp(Dp)              (eps guard dropped: |eps*sq/dp| ~ 3e-5)
// C/D layout: col=lane&31, row=(reg&3)+8*(reg>>2)+4*(lane>>5)  [R4-verified]
__global__ __launch_bounds__(256) void fused_kernel(
    const float* __restrict__ Qin, const float* __restrict__ Kin,
    const float* __restrict__ Vin,
    const float* __restrict__ W1, const float* __restrict__ W2,
    const float* __restrict__ W3, const unsigned short* __restrict__ ws,
    float* __restrict__ out)
{
    __shared__ float Vs [CC + 9][SK];      // rows l0-9 .. l0+31 (f32, band+V-frags)
    __shared__ __align__(16) unsigned short Qfb[CC][SB];  // bf16 elu1(Q)
    __shared__ __align__(16) unsigned short Kfb[CC][SB];  // bf16 elu1(K), raw
    __shared__ __align__(16) unsigned short Pb1[CC][SB];  // P relayout buffers
    __shared__ __align__(16) unsigned short Pb2[CC][SB];
    __shared__ float Ob1[CC][SK];          // branch outputs (w*z applied)
    __shared__ float Ob2[CC][SK];
    // raw-K (band) and prefix record (linear): disjoint lifetimes
    __shared__ __align__(16) union {
        float kr[(CC + 9) * SK];           // 1476 floats = 5904 B
        unsigned short sp[REC];            // 2112 shorts = 4224 B
    } U;

    const int b  = blockIdx.x;
    const int c  = b & (NCH - 1);
    const int nh = b >> 6;
    const int h  = nh & 7;
    const int n  = nh >> 3;
    const int l0 = c * CC;
    const int t  = threadIdx.x;
    const int lane = t & 31;
    const int grp  = t >> 5;       // 0..7

    // own exclusive-prefix record -> registers early (hides under A/B)
    const uint4* wbv = (const uint4*)(ws + (size_t)b * REC);
    const uint4 s0 = wbv[t];
    uint4 s1 = {0u, 0u, 0u, 0u};
    if (t < R16 - 256) s1 = wbv[256 + t];          // last 8

    // ---------------- Phase A: pure staging (no reductions) -----------------
    for (int r = grp; r < CC; r += 8) {
        const int l = l0 + r;
        const int base = ((n * LL + l) * HH + h) * EE + lane;
        const float k = Kin[base];
        const float v = Vin[base];
        const float q = Qin[base];
        Kfb[r][lane] = bfr(elu1(k));
        Qfb[r][lane] = bfr(elu1(q));
        Vs[9 + r][lane] = v;
        U.kr[(9 + r) * SK + lane] = k;
    }
    // previous 9 rows of raw K,V for the band window
    for (int idx = t; idx < 9 * 32; idx += 256) {
        const int rr = idx >> 5, ln = idx & 31;
        const int l = l0 - 9 + rr;
        float kv = 0.f, vv = 0.f;
        if (l >= 0) {
            const int gbase = ((n * LL + l) * HH + h) * EE + ln;
            kv = Kin[gbase];
            vv = Vin[gbase];
        }
        U.kr[rr * SK + ln] = kv;
        Vs[rr][ln] = vv;
    }

    // cluster identity for band and the final store
    const int r   = t >> 3;        // row 0..31
    const int sub = t & 7;
    const int d0  = sub * 4;
    const int l   = l0 + r;

    // raw Q quad in registers (band dot)
    const float4 q4 = *(const float4*)&Qin[((n * LL + l) * HH + h) * EE + d0];
    __syncthreads();

    // ---------------- Phase B: banded ONLINE softmax, cluster f4 (verbatim) --
    float bnd[4];
    {
        const float temp = 0.17677669529663687f;   // 1/sqrt(32)
        float mx = -INFINITY, den = 0.f;
        float sv0 = 0.f, sv1 = 0.f, sv2 = 0.f, sv3 = 0.f;
        #pragma unroll
        for (int jj = 0; jj < BWD; ++jj) {
            const int j = l - (BWD - 1) + jj;   // global key row
            if (j >= 0) {                        // uniform per 8-lane row group
                const float4 k4 = *(const float4*)&U.kr[(r + jj) * SK + d0];
                float p = q4.x*k4.x + q4.y*k4.y + q4.z*k4.z + q4.w*k4.w;
                p += __shfl_xor(p, 1, 8); p += __shfl_xor(p, 2, 8); p += __shfl_xor(p, 4, 8);
                const float s  = p * temp;
                const float mn = fmaxf(mx, s);
                const float c1 = __expf(mx - mn);   // 0 on first iter
                const float c2 = __expf(s - mn);
                const float4 v4 = *(const float4*)&Vs[r + jj][d0];
                den = den * c1 + c2;
                sv0 = sv0 * c1 + c2 * v4.x;
                sv1 = sv1 * c1 + c2 * v4.y;
                sv2 = sv2 * c1 + c2 * v4.z;
                sv3 = sv3 * c1 + c2 * v4.w;
                mx = mn;
            }
        }
        const float inv = 1.f / den;
        const float4 w1 = *(const float4*)&W1[h * EE + d0];
        bnd[0] = w1.x * sv0 * inv; bnd[1] = w1.y * sv1 * inv;
        bnd[2] = w1.z * sv2 * inv; bnd[3] = w1.w * sv3 * inv;
    }
    __syncthreads();   // all reads of U.kr done

    // publish own prefix record into U.sp (raw bf16 copy)
    ((uint4*)U.sp)[t] = s0;
    if (t < R16 - 256) ((uint4*)U.sp)[256 + t] = s1;
    __syncthreads();

    // ---------------- Phase C: per-branch MFMA chain (waves 0 and 2) --------
    const int wid = t >> 6;
    const int l64 = t & 63;
    const int l31 = l64 & 31;       // = A-row / B-col / C-col
    const int hi5 = l64 >> 5;       // k-half selector within frags

    if ((wid & 1) == 0) {
        const bool b2 = (wid == 2);
        const unsigned short* Spt = U.sp + (b2 ? OFF_S2 : OFF_S1); // St[d][e]
        const unsigned short* kp  = U.sp + (b2 ? OFF_K2 : OFF_K1);
        const float* Wv = b2 ? W3 : W2;
        unsigned short* Pb = b2 ? &Pb2[0][0] : &Pb1[0][0];
        float* Ob = b2 ? &Ob2[0][0] : &Ob1[0][0];

        // A-frags Qf rows; B-frags Kf^T = Kfb row reads (branch2: square both)
        s16x8 qa0 = *(const s16x8*)&Qfb[l31][8 * hi5];
        s16x8 qa1 = *(const s16x8*)&Qfb[l31][16 + 8 * hi5];
        s16x8 kb0 = *(const s16x8*)&Kfb[l31][8 * hi5];
        s16x8 kb1 = *(const s16x8*)&Kfb[l31][16 + 8 * hi5];
        if (b2) {
            #pragma unroll
            for (int i = 0; i < 8; ++i) {
                float f;
                f = bf2f((unsigned short)qa0[i]); qa0[i] = (short)bfr(f * f);
                f = bf2f((unsigned short)qa1[i]); qa1[i] = (short)bfr(f * f);
                f = bf2f((unsigned short)kb0[i]); kb0[i] = (short)bfr(f * f);
                f = bf2f((unsigned short)kb1[i]); kb1[i] = (short)bfr(f * f);
            }
        }
        s16x8 ones;
        #pragma unroll
        for (int i = 0; i < 8; ++i) ones[i] = (short)0x3F80;  // bf16 1.0

        // Dk: every lane holds sk[col] (rowsum of Kf over e, replicated)
        f32x16 Dk = {};
        Dk = __builtin_amdgcn_mfma_f32_32x32x16_bf16(ones, kb0, Dk, 0, 0, 0);
        Dk = __builtin_amdgcn_mfma_f32_32x32x16_bf16(ones, kb1, Dk, 0, 0, 0);
        // P_raw = Qf x Kf^T
        f32x16 P = {};
        P = __builtin_amdgcn_mfma_f32_32x32x16_bf16(qa0, kb0, P, 0, 0, 0);
        P = __builtin_amdgcn_mfma_f32_32x32x16_bf16(qa1, kb1, P, 0, 0, 0);

        // causal mask + per-column normalize (f32) -> row-major bf16 in LDS
        const float ki = __builtin_amdgcn_rcpf(Dk[0]);   // 1/sk[l31], sk>0
        #pragma unroll
        for (int k = 0; k < 16; ++k) {
            const int row = (k & 3) + 8 * (k >> 2) + 4 * hi5;
            Pb[row * SB + l31] = bfr((l31 <= row) ? P[k] * ki : 0.f);
        }
        const s16x8 pa0 = *(const s16x8*)&Pb[l31 * SB + 8 * hi5];
        const s16x8 pa1 = *(const s16x8*)&Pb[l31 * SB + 16 + 8 * hi5];

        // B-frags of V (scalar gather from f32 Vs)
        s16x8 vb0, vb1;
        #pragma unroll
        for (int i = 0; i < 8; ++i) {
            vb0[i] = (short)bfr(Vs[9 + 8 * hi5 + i][l31]);
            vb1[i] = (short)bfr(Vs[9 + 16 + 8 * hi5 + i][l31]);
        }
        // B-frags of S: St[d][e] row-major -> VECTOR reads (was 16-way gather)
        const s16x8 sb0 = *(const s16x8*)&Spt[l31 * EE + 8 * hi5];
        const s16x8 sb1 = *(const s16x8*)&Spt[l31 * EE + 16 + 8 * hi5];
        // B-frags of kp: broadcast vector reads
        const s16x8 rb0 = *(const s16x8*)&kp[8 * hi5];
        const s16x8 rb1 = *(const s16x8*)&kp[16 + 8 * hi5];

        f32x16 A = {};
        A = __builtin_amdgcn_mfma_f32_32x32x16_bf16(pa0, vb0, A, 0, 0, 0);  // triangle
        A = __builtin_amdgcn_mfma_f32_32x32x16_bf16(pa1, vb1, A, 0, 0, 0);
        A = __builtin_amdgcn_mfma_f32_32x32x16_bf16(qa0, sb0, A, 0, 0, 0);  // prefix
        A = __builtin_amdgcn_mfma_f32_32x32x16_bf16(qa1, sb1, A, 0, 0, 0);

        f32x16 Dp = {};
        Dp = __builtin_amdgcn_mfma_f32_32x32x16_bf16(pa0, ones, Dp, 0, 0, 0);
        Dp = __builtin_amdgcn_mfma_f32_32x32x16_bf16(pa1, ones, Dp, 0, 0, 0);
        Dp = __builtin_amdgcn_mfma_f32_32x32x16_bf16(qa0, rb0, Dp, 0, 0, 0);
        Dp = __builtin_amdgcn_mfma_f32_32x32x16_bf16(qa1, rb1, Dp, 0, 0, 0);

        // epilogue: z = 1/dp, output weight -> Ob
        const float wv = Wv[h * EE + l31];
        #pragma unroll
        for (int k = 0; k < 16; ++k) {
            const int row = (k & 3) + 8 * (k >> 2) + 4 * hi5;
            Ob[row * SK + l31] = wv * A[k] * __builtin_amdgcn_rcpf(Dp[k]);
        }
    }
    __syncthreads();

    // ---------------- final combine + single store (cluster mapping) --------
    const float4 o1 = *(const float4*)&Ob1[r][d0];
    const float4 o2 = *(const float4*)&Ob2[r][d0];
    float4 o;
    o.x = bnd[0] + o1.x + o2.x;
    o.y = bnd[1] + o1.y + o2.y;
    o.z = bnd[2] + o1.z + o2.z;
    o.w = bnd[3] + o1.w + o2.w;
    *(float4*)&out[((n * LL + l) * HH + h) * EE + d0] = o;
}

extern "C" void kernel_launch(void* const* d_in, const int* in_sizes, int n_in,
                              void* d_out, int out_size, void* d_ws, size_t ws_size,
                              hipStream_t stream)
{
    (void)in_sizes; (void)n_in; (void)out_size; (void)ws_size;
    const float* Q  = (const float*)d_in[0];
    const float* K  = (const float*)d_in[1];
    const float* V  = (const float*)d_in[2];
    // d_in[3] = key_lengths: cancels mathematically (normalization over E)
    const float* W1 = (const float*)d_in[4];
    const float* W2 = (const float*)d_in[5];
    const float* W3 = (const float*)d_in[6];
    float* out = (float*)d_out;
    unsigned short* ws = (unsigned short*)d_ws;   // NB*REC*2 = ~4.3 MB scratch

    chunksum_kernel<<<NB,           256, 0, stream>>>(K, V, ws);
    prefix_kernel  <<<NN * HH * 11, 192, 0, stream>>>(ws);
    fused_kernel   <<<NB,           256, 0, stream>>>(Q, K, V, W1, W2, W3, ws, out);
}